// Round 12
// baseline (770.549 us; speedup 1.0000x reference)
//
#include <hip/hip_runtime.h>
#include <hip/hip_cooperative_groups.h>

namespace cg = cooperative_groups;

#define FF 128
#define BCAP 8192       // per-bucket region capacity (avg ~4081 for seeded input)
#define CHUNK 4096      // edges per partA work item
#define PITCH 136
#define SMEM_BYTES 37376  // max(partA 5KB+32KB, mm2 2*17.4KB, pool 17.7KB)

typedef __attribute__((ext_vector_type(8))) short short8;
typedef __attribute__((ext_vector_type(4))) float f32x4;

__device__ __forceinline__ unsigned short bf16_rne(float f) {
    unsigned u = __float_as_uint(f);
    u += 0x7fffu + ((u >> 16) & 1u);
    return (unsigned short)(u >> 16);
}
__device__ __forceinline__ float bf16_to_f32(unsigned short h) {
    return __uint_as_float(((unsigned)h) << 16);
}

struct MegaArgs {
    const float* x;
    const int* esrc; const int* edst; const float* eval;
    const unsigned short* wh0; const unsigned short* wl0;
    const unsigned short* wh1; const unsigned short* wl1;
    const unsigned short* wh2; const unsigned short* wl2;
    const unsigned short* wh3; const unsigned short* wl3;
    const unsigned short* wh4; const unsigned short* wl4;
    const unsigned short* wh5; const unsigned short* wl5;
    const float* pb0; const float* f1b0; const float* f2b0;
    const float* pb1; const float* f1b1; const float* f2b1;
    unsigned short* h; unsigned short* hsq; unsigned short* aggh; unsigned short* x1;
    int* offsets; int* bucket_cnt;
    int2* ebuf; int2* edata;
    float* out;
    int N, E, ntiles, ngroups, nchunks, nbuck;
};

// ---------------------------------------------------------------------------
// Pool tile: h[n][j] = relu( dot(x[n],W[j]) * (1/||x[n]||) + b[j] )   (folded
// L2-norm; A single bf16 plane, 2-term MFMA). Writes h + hsq=bf16(h^2).
// ---------------------------------------------------------------------------
template<int ABF16>
__device__ __forceinline__
void pool_tile(char* smem_, const void* xin_,
               const unsigned short* __restrict__ Wh, const unsigned short* __restrict__ Wl,
               const float* __restrict__ bias,
               unsigned short* __restrict__ hout, unsigned short* __restrict__ hsqout,
               int N, int tile)
{
    unsigned short* sX = (unsigned short*)smem_;
    float* sNorm = (float*)(smem_ + 64 * PITCH * 2);
    const int tid = threadIdx.x;

    #pragma unroll
    for (int rg = 0; rg < 2; ++rg) {
        const int row = rg * 32 + (tid >> 3);
        const int c0  = (tid & 7) * 16;
        const int n   = tile * 64 + row;
        const int base = row * PITCH + c0;
        float ss = 0.f;
        if constexpr (ABF16) {
            const unsigned short* xin = (const unsigned short*)xin_;
            union { short8 s; unsigned short u[8]; } a, b;
            short8 z = {0,0,0,0,0,0,0,0};
            a.s = z; b.s = z;
            if (n < N) {
                const short8* p = (const short8*)(xin + (size_t)n * FF + c0);
                a.s = p[0]; b.s = p[1];
            }
            #pragma unroll
            for (int i = 0; i < 8; ++i) {
                float fa = bf16_to_f32(a.u[i]);
                float fb = bf16_to_f32(b.u[i]);
                ss = fmaf(fa, fa, fmaf(fb, fb, ss));
            }
            *(short8*)&sX[base]     = a.s;
            *(short8*)&sX[base + 8] = b.s;
        } else {
            const float* xin = (const float*)xin_;
            float v[16];
            if (n < N) {
                const float4* p = (const float4*)(xin + (size_t)n * FF + c0);
                #pragma unroll
                for (int i = 0; i < 4; ++i) {
                    float4 q = p[i];
                    v[4*i] = q.x; v[4*i+1] = q.y; v[4*i+2] = q.z; v[4*i+3] = q.w;
                }
            } else {
                #pragma unroll
                for (int i = 0; i < 16; ++i) v[i] = 0.f;
            }
            #pragma unroll
            for (int i = 0; i < 16; ++i) ss = fmaf(v[i], v[i], ss);
            union { unsigned short u[8]; short8 s; } h0, h1;
            #pragma unroll
            for (int i = 0; i < 8; ++i) {
                h0.u[i] = bf16_rne(v[i]);
                h1.u[i] = bf16_rne(v[8 + i]);
            }
            *(short8*)&sX[base]     = h0.s;
            *(short8*)&sX[base + 8] = h1.s;
        }
        ss += __shfl_xor(ss, 1);
        ss += __shfl_xor(ss, 2);
        ss += __shfl_xor(ss, 4);
        if ((tid & 7) == 0) sNorm[row] = 1.0f / fmaxf(sqrtf(ss), 1e-12f);
    }
    __syncthreads();

    const int lane = tid & 63, wave = tid >> 6;
    const int quad = lane >> 4, l16 = lane & 15;

    short8 Bh[2][4], Bl[2][4];
    #pragma unroll
    for (int c = 0; c < 2; ++c) {
        const int jt = 2 * wave + c;
        #pragma unroll
        for (int t = 0; t < 4; ++t) {
            const size_t o = ((size_t)(jt * 4 + t) * 64 + lane) * 8;
            Bh[c][t] = *(const short8*)&Wh[o];
            Bl[c][t] = *(const short8*)&Wl[o];
        }
    }

    f32x4 acc[4][2];
    #pragma unroll
    for (int r = 0; r < 4; ++r)
        #pragma unroll
        for (int c = 0; c < 2; ++c) {
            f32x4 z = {0.f, 0.f, 0.f, 0.f};
            acc[r][c] = z;
        }

    #pragma unroll
    for (int t = 0; t < 4; ++t) {
        short8 Ah[4];
        #pragma unroll
        for (int r = 0; r < 4; ++r)
            Ah[r] = *(const short8*)&sX[(r * 16 + l16) * PITCH + t * 32 + quad * 8];
        #pragma unroll
        for (int c = 0; c < 2; ++c)
            #pragma unroll
            for (int r = 0; r < 4; ++r) {
                acc[r][c] = __builtin_amdgcn_mfma_f32_16x16x32_bf16(Ah[r], Bh[c][t], acc[r][c], 0, 0, 0);
                acc[r][c] = __builtin_amdgcn_mfma_f32_16x16x32_bf16(Ah[r], Bl[c][t], acc[r][c], 0, 0, 0);
            }
    }

    #pragma unroll
    for (int c = 0; c < 2; ++c) {
        const int j = (2 * wave + c) * 16 + l16;
        const float bj = bias[j];
        #pragma unroll
        for (int r = 0; r < 4; ++r) {
            #pragma unroll
            for (int g = 0; g < 4; ++g) {
                const int nl = r * 16 + quad * 4 + g;
                const int n = tile * 64 + nl;
                if (n < N) {
                    float s = sNorm[nl];
                    float val = fmaf(acc[r][c][g], s, bj);
                    val = fmaxf(val, 0.f);
                    hout  [(size_t)n * FF + j] = bf16_rne(val);
                    hsqout[(size_t)n * FF + j] = bf16_rne(val * val);
                }
            }
        }
    }
    __syncthreads();   // protect sX/sNorm before next phase/iteration
}

// ---------------------------------------------------------------------------
// mm2 tile: out[n][j] = act( h@W1 + agg@W2 + b1+b2 )  (h exact bf16 2-term;
// agg bf16 hi-plane 2-term).
// ---------------------------------------------------------------------------
template<int OUT, int RELU, int OUTBF16>
__device__ __forceinline__
void mm2_tile(char* smem_,
              const unsigned short* __restrict__ hin, const unsigned short* __restrict__ aggh,
              const unsigned short* __restrict__ W1h, const unsigned short* __restrict__ W1l,
              const unsigned short* __restrict__ W2h, const unsigned short* __restrict__ W2l,
              const float* __restrict__ b1, const float* __restrict__ b2,
              void* __restrict__ out_, int N, int tile)
{
    unsigned short* sH  = (unsigned short*)smem_;
    unsigned short* sAh = (unsigned short*)(smem_ + 64 * PITCH * 2);
    const int tid = threadIdx.x;

    #pragma unroll
    for (int rg = 0; rg < 2; ++rg) {
        const int row = rg * 32 + (tid >> 3);
        const int c0  = (tid & 7) * 16;
        const int n   = tile * 64 + row;
        const int base = row * PITCH + c0;
        short8 z = {0,0,0,0,0,0,0,0};
        short8 a = z, b = z, c = z, d = z;
        if (n < N) {
            const short8* ph = (const short8*)(hin  + (size_t)n * FF + c0);
            const short8* pa = (const short8*)(aggh + (size_t)n * FF + c0);
            a = ph[0]; b = ph[1];
            c = pa[0]; d = pa[1];
        }
        *(short8*)&sH [base]     = a;
        *(short8*)&sH [base + 8] = b;
        *(short8*)&sAh[base]     = c;
        *(short8*)&sAh[base + 8] = d;
    }
    __syncthreads();

    const int lane = tid & 63, wave = tid >> 6;
    const int quad = lane >> 4, l16 = lane & 15;
    constexpr int CT = (OUT == 128) ? 2 : 1;

    short8 B1hf[CT][4], B1lf[CT][4], B2hf[CT][4], B2lf[CT][4];
    #pragma unroll
    for (int c = 0; c < CT; ++c) {
        const int jt = (OUT == 128) ? (2 * wave + c) : wave;
        #pragma unroll
        for (int t = 0; t < 4; ++t) {
            const size_t o = ((size_t)(jt * 4 + t) * 64 + lane) * 8;
            B1hf[c][t] = *(const short8*)&W1h[o];
            B1lf[c][t] = *(const short8*)&W1l[o];
            B2hf[c][t] = *(const short8*)&W2h[o];
            B2lf[c][t] = *(const short8*)&W2l[o];
        }
    }

    f32x4 acc[4][CT];
    #pragma unroll
    for (int r = 0; r < 4; ++r)
        #pragma unroll
        for (int c = 0; c < CT; ++c) {
            f32x4 z = {0.f, 0.f, 0.f, 0.f};
            acc[r][c] = z;
        }

    #pragma unroll
    for (int t = 0; t < 4; ++t) {
        short8 Hf[4], AH[4];
        #pragma unroll
        for (int r = 0; r < 4; ++r) {
            const int off = (r * 16 + l16) * PITCH + t * 32 + quad * 8;
            Hf[r] = *(const short8*)&sH[off];
            AH[r] = *(const short8*)&sAh[off];
        }
        #pragma unroll
        for (int c = 0; c < CT; ++c)
            #pragma unroll
            for (int r = 0; r < 4; ++r) {
                acc[r][c] = __builtin_amdgcn_mfma_f32_16x16x32_bf16(Hf[r], B1hf[c][t], acc[r][c], 0, 0, 0);
                acc[r][c] = __builtin_amdgcn_mfma_f32_16x16x32_bf16(Hf[r], B1lf[c][t], acc[r][c], 0, 0, 0);
                acc[r][c] = __builtin_amdgcn_mfma_f32_16x16x32_bf16(AH[r], B2hf[c][t], acc[r][c], 0, 0, 0);
                acc[r][c] = __builtin_amdgcn_mfma_f32_16x16x32_bf16(AH[r], B2lf[c][t], acc[r][c], 0, 0, 0);
            }
    }

    #pragma unroll
    for (int c = 0; c < CT; ++c) {
        const int jt = (OUT == 128) ? (2 * wave + c) : wave;
        const int j = jt * 16 + l16;
        const float bj = b1[j] + b2[j];
        #pragma unroll
        for (int r = 0; r < 4; ++r) {
            #pragma unroll
            for (int g = 0; g < 4; ++g) {
                const int n = tile * 64 + r * 16 + quad * 4 + g;
                if (n < N) {
                    float val = acc[r][c][g] + bj;
                    if constexpr (RELU) val = fmaxf(val, 0.f);
                    if constexpr (OUTBF16)
                        ((unsigned short*)out_)[(size_t)n * OUT + j] = bf16_rne(val);
                    else
                        ((float*)out_)[(size_t)n * OUT + j] = val;
                }
            }
        }
    }
    __syncthreads();
}

// ---------------------------------------------------------------------------
// partA chunk: LDS bucket-grouping of 4096 edges, coalesced run writes into
// over-provisioned per-bucket regions. bucket = dst >> 8.
// ---------------------------------------------------------------------------
__device__ __forceinline__
void partA_chunk(char* smem_, const MegaArgs& a, int ch)
{
    int* cnt   = (int*)smem_;
    int* sc    = cnt + 256;
    int* excl  = sc + 256;
    int* cur   = excl + 256;
    int* gbase = cur + 256;
    int2* staged = (int2*)(smem_ + 5 * 256 * 4);
    const int t = threadIdx.x;
    const int e0 = ch * CHUNK;
    const int n  = min(CHUNK, a.E - e0);

    cnt[t] = 0;
    __syncthreads();
    for (int i = t; i < n; i += 256)
        atomicAdd(&cnt[((unsigned)a.edst[e0 + i]) >> 8], 1);
    __syncthreads();

    sc[t] = cnt[t];
    __syncthreads();
    #pragma unroll
    for (int off = 1; off < 256; off <<= 1) {
        int v = (t >= off) ? sc[t - off] : 0;
        __syncthreads();
        sc[t] += v;
        __syncthreads();
    }
    excl[t] = sc[t] - cnt[t];
    cur[t]  = excl[t];
    if (cnt[t] > 0) gbase[t] = atomicAdd(&a.bucket_cnt[t], cnt[t]);
    __syncthreads();

    for (int i = t; i < n; i += 256) {
        int d = a.edst[e0 + i];
        int s = a.esrc[e0 + i];
        float v = a.eval[e0 + i];
        int b = ((unsigned)d) >> 8;
        int slot = atomicAdd(&cur[b], 1);
        staged[slot] = make_int2((s & 0xffff) | (d << 16), __float_as_int(v));
    }
    __syncthreads();

    for (int p = t; p < n; p += 256) {
        int2 ent = staged[p];
        int b = ((unsigned)ent.x) >> 24;
        int gpos = gbase[b] + (p - excl[b]);
        a.ebuf[(size_t)b * BCAP + gpos] = ent;
    }
    __syncthreads();
}

// ---------------------------------------------------------------------------
// partB bucket: per-dst offsets + fine dst-sorted scatter into compact edata.
// ---------------------------------------------------------------------------
__device__ __forceinline__
void partB_bucket(char* smem_, const MegaArgs& a, int b)
{
    int* pre  = (int*)smem_;
    int* hist = pre + 256;
    int* sc   = hist + 256;
    int* excl = sc + 256;
    int* cur  = excl + 256;
    const int t = threadIdx.x;

    pre[t] = (t < a.nbuck) ? a.bucket_cnt[t] : 0;
    __syncthreads();
    #pragma unroll
    for (int off = 1; off < 256; off <<= 1) {
        int v = (t >= off) ? pre[t - off] : 0;
        __syncthreads();
        pre[t] += v;
        __syncthreads();
    }
    const int base = (b == 0) ? 0 : pre[b - 1];
    const int cnt  = pre[b] - base;

    hist[t] = 0;
    __syncthreads();
    const int2* ib = a.ebuf + (size_t)b * BCAP;
    for (int i = t; i < cnt; i += 256)
        atomicAdd(&hist[(((unsigned)ib[i].x) >> 16) & 255], 1);
    __syncthreads();

    sc[t] = hist[t];
    __syncthreads();
    #pragma unroll
    for (int off = 1; off < 256; off <<= 1) {
        int v = (t >= off) ? sc[t - off] : 0;
        __syncthreads();
        sc[t] += v;
        __syncthreads();
    }
    excl[t] = sc[t] - hist[t];
    cur[t]  = excl[t];

    const int node = b * 256 + t;
    if (node <= a.N) a.offsets[node] = base + excl[t];
    __syncthreads();

    for (int i = t; i < cnt; i += 256) {
        int2 ent = ib[i];
        int l = (((unsigned)ent.x) >> 16) & 255;
        int pos = base + atomicAdd(&cur[l], 1);
        a.edata[pos] = make_int2(ent.x & 0xffff, ent.y);
    }
    __syncthreads();
}

// ---------------------------------------------------------------------------
// agg group: 8 nodes, one per 32-lane half-wave; lane covers 4 feats (8B).
// agg = sqrt( sum val * hsq[src] ) -> bf16 hi plane.
// ---------------------------------------------------------------------------
__device__ __forceinline__ void fma4(float4& a, float v, uint2 u) {
    a.x = fmaf(v, __uint_as_float(u.x << 16), a.x);
    a.y = fmaf(v, __uint_as_float(u.x & 0xffff0000u), a.y);
    a.z = fmaf(v, __uint_as_float(u.y << 16), a.z);
    a.w = fmaf(v, __uint_as_float(u.y & 0xffff0000u), a.w);
}

__device__ __forceinline__
void agg_group(const unsigned short* __restrict__ hsq, const int* __restrict__ offsets,
               const int2* __restrict__ edata, unsigned short* __restrict__ aggh,
               int N, int g)
{
    const int w = g * 8 + (threadIdx.x >> 5);
    if (w >= N) return;
    const int l = threadIdx.x & 31;
    const size_t fo = (size_t)(l * 4);
    int e = offsets[w];
    const int end = offsets[w + 1];

    float4 a0 = {0,0,0,0}, a1 = {0,0,0,0}, a2 = {0,0,0,0}, a3 = {0,0,0,0};

    if ((e & 1) && e < end) {
        int2 ed = edata[e];
        uint2 u = *(const uint2*)&hsq[(size_t)ed.x * FF + fo];
        fma4(a0, __int_as_float(ed.y), u);
        ++e;
    }
    for (; e + 3 < end; e += 4) {
        int4 p0 = *(const int4*)&edata[e];
        int4 p1 = *(const int4*)&edata[e + 2];
        uint2 u0 = *(const uint2*)&hsq[(size_t)p0.x * FF + fo];
        uint2 u1 = *(const uint2*)&hsq[(size_t)p0.z * FF + fo];
        uint2 u2 = *(const uint2*)&hsq[(size_t)p1.x * FF + fo];
        uint2 u3 = *(const uint2*)&hsq[(size_t)p1.z * FF + fo];
        fma4(a0, __int_as_float(p0.y), u0);
        fma4(a1, __int_as_float(p0.w), u1);
        fma4(a2, __int_as_float(p1.y), u2);
        fma4(a3, __int_as_float(p1.w), u3);
    }
    if (e + 1 < end) {
        int4 p = *(const int4*)&edata[e];
        uint2 u0 = *(const uint2*)&hsq[(size_t)p.x * FF + fo];
        uint2 u1 = *(const uint2*)&hsq[(size_t)p.z * FF + fo];
        fma4(a0, __int_as_float(p.y), u0);
        fma4(a1, __int_as_float(p.w), u1);
        e += 2;
    }
    if (e < end) {
        int2 ed = edata[e];
        uint2 u = *(const uint2*)&hsq[(size_t)ed.x * FF + fo];
        fma4(a0, __int_as_float(ed.y), u);
    }

    float4 r;
    r.x = sqrtf(a0.x + a1.x + a2.x + a3.x);
    r.y = sqrtf(a0.y + a1.y + a2.y + a3.y);
    r.z = sqrtf(a0.z + a1.z + a2.z + a3.z);
    r.w = sqrtf(a0.w + a1.w + a2.w + a3.w);

    uint2 hv = { (unsigned)bf16_rne(r.x) | ((unsigned)bf16_rne(r.y) << 16),
                 (unsigned)bf16_rne(r.z) | ((unsigned)bf16_rne(r.w) << 16) };
    *(uint2*)&aggh[(size_t)w * FF + fo] = hv;
}

// ---------------------------------------------------------------------------
// Cooperative mega-kernel: all phases in one launch, grid.sync between.
// Phase 1 runs partA chunks AND layer-0 pool tiles concurrently (independent).
// ---------------------------------------------------------------------------
__global__ __launch_bounds__(256, 2)
void mega_kernel(MegaArgs a)
{
    cg::grid_group grid = cg::this_grid();
    __shared__ alignas(16) char smem[SMEM_BYTES];

    // Phase 1: partA + pool layer 0
    const int p1 = a.nchunks + a.ntiles;
    for (int it = blockIdx.x; it < p1; it += gridDim.x) {
        if (it < a.nchunks) partA_chunk(smem, a, it);
        else pool_tile<0>(smem, a.x, a.wh0, a.wl0, a.pb0, a.h, a.hsq, a.N, it - a.nchunks);
    }
    __threadfence();
    grid.sync();

    // Phase 2: partB
    for (int b = blockIdx.x; b < a.nbuck; b += gridDim.x)
        partB_bucket(smem, a, b);
    __threadfence();
    grid.sync();

    // Phase 3: agg layer 0
    for (int g = blockIdx.x; g < a.ngroups; g += gridDim.x)
        agg_group(a.hsq, a.offsets, a.edata, a.aggh, a.N, g);
    __threadfence();
    grid.sync();

    // Phase 4: mm2 layer 0 -> x1 (bf16)
    for (int t = blockIdx.x; t < a.ntiles; t += gridDim.x)
        mm2_tile<128, 1, 1>(smem, a.h, a.aggh, a.wh1, a.wl1, a.wh2, a.wl2,
                            a.f1b0, a.f2b0, (void*)a.x1, a.N, t);
    __threadfence();
    grid.sync();

    // Phase 5: pool layer 1
    for (int t = blockIdx.x; t < a.ntiles; t += gridDim.x)
        pool_tile<1>(smem, a.x1, a.wh3, a.wl3, a.pb1, a.h, a.hsq, a.N, t);
    __threadfence();
    grid.sync();

    // Phase 6: agg layer 1
    for (int g = blockIdx.x; g < a.ngroups; g += gridDim.x)
        agg_group(a.hsq, a.offsets, a.edata, a.aggh, a.N, g);
    __threadfence();
    grid.sync();

    // Phase 7: mm2 layer 1 -> out (fp32)
    for (int t = blockIdx.x; t < a.ntiles; t += gridDim.x)
        mm2_tile<64, 0, 0>(smem, a.h, a.aggh, a.wh4, a.wl4, a.wh5, a.wl5,
                           a.f1b1, a.f2b1, (void*)a.out, a.N, t);
}

// ---------------------------------------------------------------------------
// Weight prep: fp32 [OUT][128] -> fragment-major bf16 hi/lo planes.
// Block 0 also zeroes bucket_cnt.
// ---------------------------------------------------------------------------
struct WPack {
    const float* src[6];
    unsigned short* hi[6];
    unsigned short* lo[6];
    int n[6];
};

__global__ __launch_bounds__(256)
void wprep_kernel(WPack p, int* __restrict__ bucket_cnt)
{
    if (blockIdx.x == 0) bucket_cnt[threadIdx.x] = 0;
    int id = blockIdx.x * 256 + threadIdx.x;
    #pragma unroll
    for (int i = 0; i < 6; ++i) {
        if (id < p.n[i]) {
            float f = p.src[i][id];
            unsigned short h = bf16_rne(f);
            const int j = id >> 7, k = id & 127;
            const int jt = j >> 4, l16 = j & 15;
            const int t = k >> 5, quad = (k >> 3) & 3, j8 = k & 7;
            const size_t o = ((size_t)((jt * 4 + t) * 4 + quad) * 16 + l16) * 8 + j8;
            p.hi[i][o] = h;
            p.lo[i][o] = bf16_rne(f - bf16_to_f32(h));
            return;
        }
        id -= p.n[i];
    }
}

// ---------------------------------------------------------------------------
extern "C" void kernel_launch(void* const* d_in, const int* in_sizes, int n_in,
                              void* d_out, int out_size, void* d_ws, size_t ws_size,
                              hipStream_t stream) {
    const float* x    = (const float*)d_in[0];
    const int*   esrc = (const int*)d_in[1];
    const int*   edst = (const int*)d_in[2];
    const float* eval = (const float*)d_in[3];
    const float* pw0  = (const float*)d_in[4];
    const float* pb0  = (const float*)d_in[5];
    const float* f1w0 = (const float*)d_in[6];
    const float* f1b0 = (const float*)d_in[7];
    const float* f2w0 = (const float*)d_in[8];
    const float* f2b0 = (const float*)d_in[9];
    const float* pw1  = (const float*)d_in[10];
    const float* pb1  = (const float*)d_in[11];
    const float* f1w1 = (const float*)d_in[12];
    const float* f1b1 = (const float*)d_in[13];
    const float* f2w1 = (const float*)d_in[14];
    const float* f2b1 = (const float*)d_in[15];
    float* out = (float*)d_out;

    const int N = in_sizes[0] / FF;     // 50000  (must be <= 65536 for 16-bit packing)
    const int E = in_sizes[1];          // 800000
    const int nbuck = (N + 255) / 256;  // 196

    char* ws = (char*)d_ws;
    const size_t planesz = (size_t)N * FF * 2;                    // 12.8 MB bf16 plane
    const size_t A = 256;
    size_t off = 0;
    unsigned short* h    = (unsigned short*)(ws + off); off += (planesz + A - 1) / A * A;
    unsigned short* hsq  = (unsigned short*)(ws + off); off += (planesz + A - 1) / A * A;
    unsigned short* aggh = (unsigned short*)(ws + off); off += (planesz + A - 1) / A * A;
    unsigned short* x1   = (unsigned short*)(ws + off); off += (planesz + A - 1) / A * A;
    int* offsets = (int*)(ws + off); off += ((size_t)(N + 1) * 4 + A - 1) / A * A;
    int* bucket_cnt = (int*)(ws + off); off += (size_t)256 * 4;
    int2* ebuf  = (int2*)(ws + off); off += (size_t)nbuck * BCAP * 8;   // 12.8 MB
    int2* edata = (int2*)(ws + off); off += (size_t)E * 8;
    const int wsz[6] = {128 * FF, 128 * FF, 128 * FF, 128 * FF, 64 * FF, 64 * FF};
    unsigned short* whi[6];
    unsigned short* wlo[6];
    for (int i = 0; i < 6; ++i) {
        whi[i] = (unsigned short*)(ws + off); off += (size_t)wsz[i] * 2;
        wlo[i] = (unsigned short*)(ws + off); off += (size_t)wsz[i] * 2;
    }

    WPack pack;
    const float* wsrc[6] = {pw0, f1w0, f2w0, pw1, f1w1, f2w1};
    int wtotal = 0;
    for (int i = 0; i < 6; ++i) {
        pack.src[i] = wsrc[i]; pack.hi[i] = whi[i]; pack.lo[i] = wlo[i]; pack.n[i] = wsz[i];
        wtotal += wsz[i];
    }

    dim3 B(256);

    // ---- weight prep (fragment-major bf16 split) + bucket_cnt zero ----
    wprep_kernel<<<(wtotal + 255) / 256, B, 0, stream>>>(pack, bucket_cnt);

    // ---- cooperative mega-kernel: partition + both layers ----
    MegaArgs ma;
    ma.x = x; ma.esrc = esrc; ma.edst = edst; ma.eval = eval;
    ma.wh0 = whi[0]; ma.wl0 = wlo[0];
    ma.wh1 = whi[1]; ma.wl1 = wlo[1];
    ma.wh2 = whi[2]; ma.wl2 = wlo[2];
    ma.wh3 = whi[3]; ma.wl3 = wlo[3];
    ma.wh4 = whi[4]; ma.wl4 = wlo[4];
    ma.wh5 = whi[5]; ma.wl5 = wlo[5];
    ma.pb0 = pb0; ma.f1b0 = f1b0; ma.f2b0 = f2b0;
    ma.pb1 = pb1; ma.f1b1 = f1b1; ma.f2b1 = f2b1;
    ma.h = h; ma.hsq = hsq; ma.aggh = aggh; ma.x1 = x1;
    ma.offsets = offsets; ma.bucket_cnt = bucket_cnt;
    ma.ebuf = ebuf; ma.edata = edata;
    ma.out = out;
    ma.N = N; ma.E = E;
    ma.ntiles  = (N + 63) / 64;
    ma.ngroups = (N + 7) / 8;
    ma.nchunks = (E + CHUNK - 1) / CHUNK;
    ma.nbuck   = nbuck;

    int nb = 0;
    hipOccupancyMaxActiveBlocksPerMultiprocessor(&nb, mega_kernel, 256, 0);
    if (nb < 1) nb = 1;
    int grid = nb * 256;          // 256 CUs on MI355X; co-residency guaranteed by query
    if (grid > 2048) grid = 2048;

    void* kargs[] = { (void*)&ma };
    hipLaunchCooperativeKernel(mega_kernel, dim3(grid), B, kargs, (unsigned)0, stream);
}

// Round 13
// 245.485 us; speedup vs baseline: 3.1389x; 3.1389x over previous
//
#include <hip/hip_runtime.h>

#define FF 128
#define BCAP 8192       // per-bucket region capacity (avg ~4081 for seeded input)
#define CHUNK 4096      // edges per partA block
#define PITCH 136

typedef __attribute__((ext_vector_type(8))) short short8;
typedef __attribute__((ext_vector_type(4))) float f32x4;

__device__ __forceinline__ unsigned short bf16_rne(float f) {
    unsigned u = __float_as_uint(f);
    u += 0x7fffu + ((u >> 16) & 1u);
    return (unsigned short)(u >> 16);
}
__device__ __forceinline__ float bf16_to_f32(unsigned short h) {
    return __uint_as_float(((unsigned)h) << 16);
}

// ---------------------------------------------------------------------------
// Fused partA + pool layer 0 (independent work, one dispatch):
//  - blocks [0, nchunks): LDS bucket partition of 4096-edge chunks
//  - blocks [nchunks, ...): pool tiles, folded L2-norm, h + hsq bf16 out
// Shared memory is a union (partA needs 37,888 B; pool 17,664 B).
// ---------------------------------------------------------------------------
__global__ __launch_bounds__(256, 2)
void poolpartA_kernel(const float* __restrict__ x,
                      const unsigned short* __restrict__ Wh, const unsigned short* __restrict__ Wl,
                      const float* __restrict__ bias,
                      unsigned short* __restrict__ hout, unsigned short* __restrict__ hsqout,
                      const int* __restrict__ esrc, const int* __restrict__ edst,
                      const float* __restrict__ eval,
                      int* __restrict__ bucket_cnt, int2* __restrict__ ebuf,
                      int N, int E, int nchunks)
{
    __shared__ alignas(16) char smem[37888];
    const int t = threadIdx.x;

    if (blockIdx.x < nchunks) {
        // ---------------- partA chunk ----------------
        int* cnt   = (int*)smem;
        int* sc    = cnt + 256;
        int* excl  = sc + 256;
        int* cur   = excl + 256;
        int* gbase = cur + 256;
        int2* staged = (int2*)(smem + 5 * 256 * 4);
        const int e0 = blockIdx.x * CHUNK;
        const int n  = min(CHUNK, E - e0);

        cnt[t] = 0;
        __syncthreads();
        for (int i = t; i < n; i += 256)
            atomicAdd(&cnt[((unsigned)edst[e0 + i]) >> 8], 1);
        __syncthreads();

        sc[t] = cnt[t];
        __syncthreads();
        #pragma unroll
        for (int off = 1; off < 256; off <<= 1) {
            int v = (t >= off) ? sc[t - off] : 0;
            __syncthreads();
            sc[t] += v;
            __syncthreads();
        }
        excl[t] = sc[t] - cnt[t];
        cur[t]  = excl[t];
        if (cnt[t] > 0) gbase[t] = atomicAdd(&bucket_cnt[t], cnt[t]);
        __syncthreads();

        for (int i = t; i < n; i += 256) {
            int d = edst[e0 + i];
            int s = esrc[e0 + i];
            float v = eval[e0 + i];
            int b = ((unsigned)d) >> 8;
            int slot = atomicAdd(&cur[b], 1);
            staged[slot] = make_int2((s & 0xffff) | (d << 16), __float_as_int(v));
        }
        __syncthreads();

        for (int p = t; p < n; p += 256) {
            int2 ent = staged[p];
            int b = ((unsigned)ent.x) >> 24;
            int gpos = gbase[b] + (p - excl[b]);
            ebuf[(size_t)b * BCAP + gpos] = ent;
        }
    } else {
        // ---------------- pool tile (layer 0, fp32 input) ----------------
        unsigned short* sX = (unsigned short*)smem;
        float* sNorm = (float*)(smem + 64 * PITCH * 2);
        const int tile = blockIdx.x - nchunks;

        #pragma unroll
        for (int rg = 0; rg < 2; ++rg) {
            const int row = rg * 32 + (t >> 3);
            const int c0  = (t & 7) * 16;
            const int n   = tile * 64 + row;
            const int base = row * PITCH + c0;
            float v[16];
            if (n < N) {
                const float4* p = (const float4*)(x + (size_t)n * FF + c0);
                #pragma unroll
                for (int i = 0; i < 4; ++i) {
                    float4 q = p[i];
                    v[4*i] = q.x; v[4*i+1] = q.y; v[4*i+2] = q.z; v[4*i+3] = q.w;
                }
            } else {
                #pragma unroll
                for (int i = 0; i < 16; ++i) v[i] = 0.f;
            }
            float ss = 0.f;
            #pragma unroll
            for (int i = 0; i < 16; ++i) ss = fmaf(v[i], v[i], ss);
            union { unsigned short u[8]; short8 s; } h0, h1;
            #pragma unroll
            for (int i = 0; i < 8; ++i) {
                h0.u[i] = bf16_rne(v[i]);
                h1.u[i] = bf16_rne(v[8 + i]);
            }
            *(short8*)&sX[base]     = h0.s;
            *(short8*)&sX[base + 8] = h1.s;
            ss += __shfl_xor(ss, 1);
            ss += __shfl_xor(ss, 2);
            ss += __shfl_xor(ss, 4);
            if ((t & 7) == 0) sNorm[row] = 1.0f / fmaxf(sqrtf(ss), 1e-12f);
        }
        __syncthreads();

        const int lane = t & 63, wave = t >> 6;
        const int quad = lane >> 4, l16 = lane & 15;

        short8 Bh[2][4], Bl[2][4];
        #pragma unroll
        for (int c = 0; c < 2; ++c) {
            const int jt = 2 * wave + c;
            #pragma unroll
            for (int tt = 0; tt < 4; ++tt) {
                const size_t o = ((size_t)(jt * 4 + tt) * 64 + lane) * 8;
                Bh[c][tt] = *(const short8*)&Wh[o];
                Bl[c][tt] = *(const short8*)&Wl[o];
            }
        }

        f32x4 acc[4][2];
        #pragma unroll
        for (int r = 0; r < 4; ++r)
            #pragma unroll
            for (int c = 0; c < 2; ++c) {
                f32x4 z = {0.f, 0.f, 0.f, 0.f};
                acc[r][c] = z;
            }

        #pragma unroll
        for (int tt = 0; tt < 4; ++tt) {
            short8 Ah[4];
            #pragma unroll
            for (int r = 0; r < 4; ++r)
                Ah[r] = *(const short8*)&sX[(r * 16 + l16) * PITCH + tt * 32 + quad * 8];
            #pragma unroll
            for (int c = 0; c < 2; ++c)
                #pragma unroll
                for (int r = 0; r < 4; ++r) {
                    acc[r][c] = __builtin_amdgcn_mfma_f32_16x16x32_bf16(Ah[r], Bh[c][tt], acc[r][c], 0, 0, 0);
                    acc[r][c] = __builtin_amdgcn_mfma_f32_16x16x32_bf16(Ah[r], Bl[c][tt], acc[r][c], 0, 0, 0);
                }
        }

        #pragma unroll
        for (int c = 0; c < 2; ++c) {
            const int j = (2 * wave + c) * 16 + l16;
            const float bj = bias[j];
            #pragma unroll
            for (int r = 0; r < 4; ++r) {
                #pragma unroll
                for (int g = 0; g < 4; ++g) {
                    const int nl = r * 16 + quad * 4 + g;
                    const int n = tile * 64 + nl;
                    if (n < N) {
                        float s = sNorm[nl];
                        float val = fmaf(acc[r][c][g], s, bj);
                        val = fmaxf(val, 0.f);
                        hout  [(size_t)n * FF + j] = bf16_rne(val);
                        hsqout[(size_t)n * FF + j] = bf16_rne(val * val);
                    }
                }
            }
        }
    }
}

// ---------------------------------------------------------------------------
// Pool (layer 1, bf16 input) — standalone, folded L2-norm, h + hsq out.
// ---------------------------------------------------------------------------
__global__ __launch_bounds__(256, 2)
void pool_mfma_bf16(const unsigned short* __restrict__ xin,
                    const unsigned short* __restrict__ Wh, const unsigned short* __restrict__ Wl,
                    const float* __restrict__ bias,
                    unsigned short* __restrict__ hout, unsigned short* __restrict__ hsqout, int N)
{
    __shared__ unsigned short sX[64 * PITCH];
    __shared__ float sNorm[64];

    const int tid  = threadIdx.x;
    const int tile = blockIdx.x;

    #pragma unroll
    for (int rg = 0; rg < 2; ++rg) {
        const int row = rg * 32 + (tid >> 3);
        const int c0  = (tid & 7) * 16;
        const int n   = tile * 64 + row;
        const int base = row * PITCH + c0;
        union { short8 s; unsigned short u[8]; } a, b;
        short8 z = {0,0,0,0,0,0,0,0};
        a.s = z; b.s = z;
        if (n < N) {
            const short8* p = (const short8*)(xin + (size_t)n * FF + c0);
            a.s = p[0]; b.s = p[1];
        }
        float ss = 0.f;
        #pragma unroll
        for (int i = 0; i < 8; ++i) {
            float fa = bf16_to_f32(a.u[i]);
            float fb = bf16_to_f32(b.u[i]);
            ss = fmaf(fa, fa, fmaf(fb, fb, ss));
        }
        *(short8*)&sX[base]     = a.s;
        *(short8*)&sX[base + 8] = b.s;
        ss += __shfl_xor(ss, 1);
        ss += __shfl_xor(ss, 2);
        ss += __shfl_xor(ss, 4);
        if ((tid & 7) == 0) sNorm[row] = 1.0f / fmaxf(sqrtf(ss), 1e-12f);
    }
    __syncthreads();

    const int lane = tid & 63, wave = tid >> 6;
    const int quad = lane >> 4, l16 = lane & 15;

    short8 Bh[2][4], Bl[2][4];
    #pragma unroll
    for (int c = 0; c < 2; ++c) {
        const int jt = 2 * wave + c;
        #pragma unroll
        for (int t = 0; t < 4; ++t) {
            const size_t o = ((size_t)(jt * 4 + t) * 64 + lane) * 8;
            Bh[c][t] = *(const short8*)&Wh[o];
            Bl[c][t] = *(const short8*)&Wl[o];
        }
    }

    f32x4 acc[4][2];
    #pragma unroll
    for (int r = 0; r < 4; ++r)
        #pragma unroll
        for (int c = 0; c < 2; ++c) {
            f32x4 z = {0.f, 0.f, 0.f, 0.f};
            acc[r][c] = z;
        }

    #pragma unroll
    for (int t = 0; t < 4; ++t) {
        short8 Ah[4];
        #pragma unroll
        for (int r = 0; r < 4; ++r)
            Ah[r] = *(const short8*)&sX[(r * 16 + l16) * PITCH + t * 32 + quad * 8];
        #pragma unroll
        for (int c = 0; c < 2; ++c)
            #pragma unroll
            for (int r = 0; r < 4; ++r) {
                acc[r][c] = __builtin_amdgcn_mfma_f32_16x16x32_bf16(Ah[r], Bh[c][t], acc[r][c], 0, 0, 0);
                acc[r][c] = __builtin_amdgcn_mfma_f32_16x16x32_bf16(Ah[r], Bl[c][t], acc[r][c], 0, 0, 0);
            }
    }

    #pragma unroll
    for (int c = 0; c < 2; ++c) {
        const int j = (2 * wave + c) * 16 + l16;
        const float bj = bias[j];
        #pragma unroll
        for (int r = 0; r < 4; ++r) {
            #pragma unroll
            for (int g = 0; g < 4; ++g) {
                const int nl = r * 16 + quad * 4 + g;
                const int n = tile * 64 + nl;
                if (n < N) {
                    float s = sNorm[nl];
                    float val = fmaf(acc[r][c][g], s, bj);
                    val = fmaxf(val, 0.f);
                    hout  [(size_t)n * FF + j] = bf16_rne(val);
                    hsqout[(size_t)n * FF + j] = bf16_rne(val * val);
                }
            }
        }
    }
}

// ---------------------------------------------------------------------------
// Fused fc1+fc2: out[n][j] = act( h@W1 + agg@W2 + b1+b2 )  (h exact bf16
// 2-term; agg bf16 hi-plane 2-term). OUTBF16: bf16 (x1) vs fp32 (final out).
// ---------------------------------------------------------------------------
template<int OUT, int RELU, int OUTBF16>
__global__ __launch_bounds__(256, 2)
void mm2_mfma(const unsigned short* __restrict__ hin,
              const unsigned short* __restrict__ aggh,
              const unsigned short* __restrict__ W1h, const unsigned short* __restrict__ W1l,
              const unsigned short* __restrict__ W2h, const unsigned short* __restrict__ W2l,
              const float* __restrict__ b1, const float* __restrict__ b2,
              void* __restrict__ out_, int N)
{
    __shared__ unsigned short sH [64 * PITCH];
    __shared__ unsigned short sAh[64 * PITCH];

    const int tid  = threadIdx.x;
    const int tile = blockIdx.x;

    #pragma unroll
    for (int rg = 0; rg < 2; ++rg) {
        const int row = rg * 32 + (tid >> 3);
        const int c0  = (tid & 7) * 16;
        const int n   = tile * 64 + row;
        const int base = row * PITCH + c0;
        short8 z = {0,0,0,0,0,0,0,0};
        short8 a = z, b = z, c = z, d = z;
        if (n < N) {
            const short8* ph = (const short8*)(hin  + (size_t)n * FF + c0);
            const short8* pa = (const short8*)(aggh + (size_t)n * FF + c0);
            a = ph[0]; b = ph[1];
            c = pa[0]; d = pa[1];
        }
        *(short8*)&sH [base]     = a;
        *(short8*)&sH [base + 8] = b;
        *(short8*)&sAh[base]     = c;
        *(short8*)&sAh[base + 8] = d;
    }
    __syncthreads();

    const int lane = tid & 63, wave = tid >> 6;
    const int quad = lane >> 4, l16 = lane & 15;
    constexpr int CT = (OUT == 128) ? 2 : 1;

    short8 B1hf[CT][4], B1lf[CT][4], B2hf[CT][4], B2lf[CT][4];
    #pragma unroll
    for (int c = 0; c < CT; ++c) {
        const int jt = (OUT == 128) ? (2 * wave + c) : wave;
        #pragma unroll
        for (int t = 0; t < 4; ++t) {
            const size_t o = ((size_t)(jt * 4 + t) * 64 + lane) * 8;
            B1hf[c][t] = *(const short8*)&W1h[o];
            B1lf[c][t] = *(const short8*)&W1l[o];
            B2hf[c][t] = *(const short8*)&W2h[o];
            B2lf[c][t] = *(const short8*)&W2l[o];
        }
    }

    f32x4 acc[4][CT];
    #pragma unroll
    for (int r = 0; r < 4; ++r)
        #pragma unroll
        for (int c = 0; c < CT; ++c) {
            f32x4 z = {0.f, 0.f, 0.f, 0.f};
            acc[r][c] = z;
        }

    #pragma unroll
    for (int t = 0; t < 4; ++t) {
        short8 Hf[4], AH[4];
        #pragma unroll
        for (int r = 0; r < 4; ++r) {
            const int off = (r * 16 + l16) * PITCH + t * 32 + quad * 8;
            Hf[r] = *(const short8*)&sH[off];
            AH[r] = *(const short8*)&sAh[off];
        }
        #pragma unroll
        for (int c = 0; c < CT; ++c)
            #pragma unroll
            for (int r = 0; r < 4; ++r) {
                acc[r][c] = __builtin_amdgcn_mfma_f32_16x16x32_bf16(Hf[r], B1hf[c][t], acc[r][c], 0, 0, 0);
                acc[r][c] = __builtin_amdgcn_mfma_f32_16x16x32_bf16(Hf[r], B1lf[c][t], acc[r][c], 0, 0, 0);
                acc[r][c] = __builtin_amdgcn_mfma_f32_16x16x32_bf16(AH[r], B2hf[c][t], acc[r][c], 0, 0, 0);
                acc[r][c] = __builtin_amdgcn_mfma_f32_16x16x32_bf16(AH[r], B2lf[c][t], acc[r][c], 0, 0, 0);
            }
    }

    #pragma unroll
    for (int c = 0; c < CT; ++c) {
        const int jt = (OUT == 128) ? (2 * wave + c) : wave;
        const int j = jt * 16 + l16;
        const float bj = b1[j] + b2[j];
        #pragma unroll
        for (int r = 0; r < 4; ++r) {
            #pragma unroll
            for (int g = 0; g < 4; ++g) {
                const int n = tile * 64 + r * 16 + quad * 4 + g;
                if (n < N) {
                    float val = acc[r][c][g] + bj;
                    if constexpr (RELU) val = fmaxf(val, 0.f);
                    if constexpr (OUTBF16)
                        ((unsigned short*)out_)[(size_t)n * OUT + j] = bf16_rne(val);
                    else
                        ((float*)out_)[(size_t)n * OUT + j] = val;
                }
            }
        }
    }
}

// ---------------------------------------------------------------------------
// Weight prep: fp32 [OUT][128] -> fragment-major bf16 hi/lo planes.
// Block 0 also zeroes bucket_cnt.
// ---------------------------------------------------------------------------
struct WPack {
    const float* src[6];
    unsigned short* hi[6];
    unsigned short* lo[6];
    int n[6];
};

__global__ __launch_bounds__(256)
void wprep_kernel(WPack p, int* __restrict__ bucket_cnt)
{
    if (blockIdx.x == 0) bucket_cnt[threadIdx.x] = 0;
    int id = blockIdx.x * 256 + threadIdx.x;
    #pragma unroll
    for (int i = 0; i < 6; ++i) {
        if (id < p.n[i]) {
            float f = p.src[i][id];
            unsigned short h = bf16_rne(f);
            const int j = id >> 7, k = id & 127;
            const int jt = j >> 4, l16 = j & 15;
            const int t = k >> 5, quad = (k >> 3) & 3, j8 = k & 7;
            const size_t o = ((size_t)((jt * 4 + t) * 4 + quad) * 16 + l16) * 8 + j8;
            p.hi[i][o] = h;
            p.lo[i][o] = bf16_rne(f - bf16_to_f32(h));
            return;
        }
        id -= p.n[i];
    }
}

// ---------------------------------------------------------------------------
// Pass B: per-bucket fine sort. One block per bucket. Computes per-dst offsets,
// then scatters final edata {src, val} into the bucket's compact region.
// ---------------------------------------------------------------------------
__global__ __launch_bounds__(256)
void partB_kernel(const int* __restrict__ bucket_cnt, const int2* __restrict__ ebuf,
                  int* __restrict__ offsets, int2* __restrict__ edata,
                  int N, int E, int nbuck)
{
    __shared__ int pre[256], hist[256], sc[256], excl[256], cur[256];
    const int t = threadIdx.x;
    const int b = blockIdx.x;

    pre[t] = (t < nbuck) ? bucket_cnt[t] : 0;
    __syncthreads();
    #pragma unroll
    for (int off = 1; off < 256; off <<= 1) {
        int v = (t >= off) ? pre[t - off] : 0;
        __syncthreads();
        pre[t] += v;
        __syncthreads();
    }
    const int base = (b == 0) ? 0 : pre[b - 1];
    const int cnt  = pre[b] - base;

    hist[t] = 0;
    __syncthreads();
    const int2* ib = ebuf + (size_t)b * BCAP;
    for (int i = t; i < cnt; i += 256)
        atomicAdd(&hist[(((unsigned)ib[i].x) >> 16) & 255], 1);
    __syncthreads();

    sc[t] = hist[t];
    __syncthreads();
    #pragma unroll
    for (int off = 1; off < 256; off <<= 1) {
        int v = (t >= off) ? sc[t - off] : 0;
        __syncthreads();
        sc[t] += v;
        __syncthreads();
    }
    excl[t] = sc[t] - hist[t];
    cur[t]  = excl[t];

    const int node = b * 256 + t;
    if (node <= N) offsets[node] = base + excl[t];
    __syncthreads();

    for (int i = t; i < cnt; i += 256) {
        int2 ent = ib[i];
        int l = (((unsigned)ent.x) >> 16) & 255;
        int pos = base + atomicAdd(&cur[l], 1);
        edata[pos] = make_int2(ent.x & 0xffff, ent.y);
    }
}

// ---------------------------------------------------------------------------
// CSR aggregation over bf16 hsq: one node per 32-lane group (8 nodes/block);
// lane covers 4 feats (one 8B read). agg = sqrt(sum val*hsq) -> bf16 hi plane.
// ---------------------------------------------------------------------------
__device__ __forceinline__ void fma4(float4& a, float v, uint2 u) {
    a.x = fmaf(v, __uint_as_float(u.x << 16), a.x);
    a.y = fmaf(v, __uint_as_float(u.x & 0xffff0000u), a.y);
    a.z = fmaf(v, __uint_as_float(u.y << 16), a.z);
    a.w = fmaf(v, __uint_as_float(u.y & 0xffff0000u), a.w);
}

__global__ __launch_bounds__(256)
void agg_kernel(const unsigned short* __restrict__ hsq, const int* __restrict__ offsets,
                const int2* __restrict__ edata,
                unsigned short* __restrict__ aggh, int N)
{
    const int w = blockIdx.x * 8 + (threadIdx.x >> 5);
    if (w >= N) return;
    const int l = threadIdx.x & 31;
    const size_t fo = (size_t)(l * 4);
    int e = offsets[w];
    const int end = offsets[w + 1];

    float4 a0 = {0,0,0,0}, a1 = {0,0,0,0}, a2 = {0,0,0,0}, a3 = {0,0,0,0};

    if ((e & 1) && e < end) {
        int2 ed = edata[e];
        uint2 u = *(const uint2*)&hsq[(size_t)ed.x * FF + fo];
        fma4(a0, __int_as_float(ed.y), u);
        ++e;
    }
    for (; e + 3 < end; e += 4) {
        int4 p0 = *(const int4*)&edata[e];
        int4 p1 = *(const int4*)&edata[e + 2];
        uint2 u0 = *(const uint2*)&hsq[(size_t)p0.x * FF + fo];
        uint2 u1 = *(const uint2*)&hsq[(size_t)p0.z * FF + fo];
        uint2 u2 = *(const uint2*)&hsq[(size_t)p1.x * FF + fo];
        uint2 u3 = *(const uint2*)&hsq[(size_t)p1.z * FF + fo];
        fma4(a0, __int_as_float(p0.y), u0);
        fma4(a1, __int_as_float(p0.w), u1);
        fma4(a2, __int_as_float(p1.y), u2);
        fma4(a3, __int_as_float(p1.w), u3);
    }
    if (e + 1 < end) {
        int4 p = *(const int4*)&edata[e];
        uint2 u0 = *(const uint2*)&hsq[(size_t)p.x * FF + fo];
        uint2 u1 = *(const uint2*)&hsq[(size_t)p.z * FF + fo];
        fma4(a0, __int_as_float(p.y), u0);
        fma4(a1, __int_as_float(p.w), u1);
        e += 2;
    }
    if (e < end) {
        int2 ed = edata[e];
        uint2 u = *(const uint2*)&hsq[(size_t)ed.x * FF + fo];
        fma4(a0, __int_as_float(ed.y), u);
    }

    float4 r;
    r.x = sqrtf(a0.x + a1.x + a2.x + a3.x);
    r.y = sqrtf(a0.y + a1.y + a2.y + a3.y);
    r.z = sqrtf(a0.z + a1.z + a2.z + a3.z);
    r.w = sqrtf(a0.w + a1.w + a2.w + a3.w);

    uint2 hv = { (unsigned)bf16_rne(r.x) | ((unsigned)bf16_rne(r.y) << 16),
                 (unsigned)bf16_rne(r.z) | ((unsigned)bf16_rne(r.w) << 16) };
    *(uint2*)&aggh[(size_t)w * FF + fo] = hv;
}

// ---------------------------------------------------------------------------
extern "C" void kernel_launch(void* const* d_in, const int* in_sizes, int n_in,
                              void* d_out, int out_size, void* d_ws, size_t ws_size,
                              hipStream_t stream) {
    const float* x    = (const float*)d_in[0];
    const int*   esrc = (const int*)d_in[1];
    const int*   edst = (const int*)d_in[2];
    const float* eval = (const float*)d_in[3];
    const float* pw0  = (const float*)d_in[4];
    const float* pb0  = (const float*)d_in[5];
    const float* f1w0 = (const float*)d_in[6];
    const float* f1b0 = (const float*)d_in[7];
    const float* f2w0 = (const float*)d_in[8];
    const float* f2b0 = (const float*)d_in[9];
    const float* pw1  = (const float*)d_in[10];
    const float* pb1  = (const float*)d_in[11];
    const float* f1w1 = (const float*)d_in[12];
    const float* f1b1 = (const float*)d_in[13];
    const float* f2w1 = (const float*)d_in[14];
    const float* f2b1 = (const float*)d_in[15];
    float* out = (float*)d_out;

    const int N = in_sizes[0] / FF;     // 50000  (must be <= 65536 for 16-bit packing)
    const int E = in_sizes[1];          // 800000
    const int nbuck = (N + 255) / 256;  // 196

    char* ws = (char*)d_ws;
    const size_t planesz = (size_t)N * FF * 2;                    // 12.8 MB bf16 plane
    const size_t A = 256;
    size_t off = 0;
    unsigned short* h    = (unsigned short*)(ws + off); off += (planesz + A - 1) / A * A;
    unsigned short* hsq  = (unsigned short*)(ws + off); off += (planesz + A - 1) / A * A;
    unsigned short* aggh = (unsigned short*)(ws + off); off += (planesz + A - 1) / A * A;
    unsigned short* x1   = (unsigned short*)(ws + off); off += (planesz + A - 1) / A * A;
    int* offsets = (int*)(ws + off); off += ((size_t)(N + 1) * 4 + A - 1) / A * A;
    int* bucket_cnt = (int*)(ws + off); off += (size_t)256 * 4;
    int2* ebuf  = (int2*)(ws + off); off += (size_t)nbuck * BCAP * 8;   // 12.8 MB
    int2* edata = (int2*)(ws + off); off += (size_t)E * 8;
    const int wsz[6] = {128 * FF, 128 * FF, 128 * FF, 128 * FF, 64 * FF, 64 * FF};
    unsigned short* whi[6];
    unsigned short* wlo[6];
    for (int i = 0; i < 6; ++i) {
        whi[i] = (unsigned short*)(ws + off); off += (size_t)wsz[i] * 2;
        wlo[i] = (unsigned short*)(ws + off); off += (size_t)wsz[i] * 2;
    }

    WPack pack;
    const float* wsrc[6] = {pw0, f1w0, f2w0, pw1, f1w1, f2w1};
    int wtotal = 0;
    for (int i = 0; i < 6; ++i) {
        pack.src[i] = wsrc[i]; pack.hi[i] = whi[i]; pack.lo[i] = wlo[i]; pack.n[i] = wsz[i];
        wtotal += wsz[i];
    }

    const int ntiles     = (N + 63) / 64;
    const int nodeblocks = (N + 7) / 8;
    const int nchunks    = (E + CHUNK - 1) / CHUNK;
    dim3 B(256);

    // ---- 1: weight prep (fragment-major bf16 split) + bucket_cnt zero ----
    wprep_kernel<<<(wtotal + 255) / 256, B, 0, stream>>>(pack, bucket_cnt);

    // ---- 2: fused partA + pool layer 0 (independent work, one dispatch) ----
    poolpartA_kernel<<<nchunks + ntiles, B, 0, stream>>>(
        x, whi[0], wlo[0], pb0, h, hsq, esrc, edst, eval, bucket_cnt, ebuf, N, E, nchunks);

    // ---- 3: partB (dst-sorted edata + offsets) ----
    partB_kernel<<<nbuck, B, 0, stream>>>(bucket_cnt, ebuf, offsets, edata, N, E, nbuck);

    // ---- 4: agg layer 0 ----
    agg_kernel<<<nodeblocks, B, 0, stream>>>(hsq, offsets, edata, aggh, N);

    // ---- 5: mm2 layer 0 -> x1 (bf16) ----
    mm2_mfma<128, 1, 1><<<ntiles, B, 0, stream>>>(h, aggh, whi[1], wlo[1], whi[2], wlo[2], f1b0, f2b0, x1, N);

    // ---- 6: pool layer 1 ----
    pool_mfma_bf16<<<ntiles, B, 0, stream>>>(x1, whi[3], wlo[3], pb1, h, hsq, N);

    // ---- 7: agg layer 1 ----
    agg_kernel<<<nodeblocks, B, 0, stream>>>(hsq, offsets, edata, aggh, N);

    // ---- 8: mm2 layer 1 -> out (fp32) ----
    mm2_mfma<64, 0, 0><<<ntiles, B, 0, stream>>>(h, aggh, whi[4], wlo[4], whi[5], wlo[5], f1b1, f2b1, out, N);
}